// Round 17
// baseline (413.875 us; speedup 1.0000x reference)
//
#include <hip/hip_runtime.h>
#include <hip/hip_bf16.h>
#include <hip/hip_cooperative_groups.h>

namespace cg = cooperative_groups;

#define Bq   8
#define Tq   16
#define Nq   1024
#define Cq   48
#define Gq   32
#define Hq   150
#define H3q  450
#define TAq  32
#define OUTq 1024
#define BTq  128

#define NC_CAP 128   // active code / neighbor rows per (b,t): Binom(1024,.06) mean 61 sd 7.6
#define NM_CAP 64    // m1 / m23 rows per (b,t): Binom(1024,.03) mean 30.7 sd 5.5
#define NACT   (2 * NC_CAP)
#define MTILE  16
#define NMH    (NM_CAP / 2)

__device__ __forceinline__ float lrelu(float x){ return x > 0.f ? x : 0.01f * x; }
__device__ __forceinline__ float sigm(float x){ return 1.f / (1.f + expf(-x)); }

// -------- device-global scratch (everything read is written in an earlier phase) --------
__device__ int   g_n1[BTq], g_n23[BTq], g_nchain[BTq], g_nchain2[BTq];
__device__ short g_list1[BTq][NM_CAP];
__device__ short g_list23[BTq][NM_CAP];        // row | (m2 ? 0x400 : 0), ascending row order
__device__ short g_mapc[BTq][Nq];              // row -> slot in c-list (-1 if inactive)
__device__ short g_mapn[BTq][Nq];              // row -> slot in nb-list (-1 if inactive)
__device__ int   g_chain[BTq][NM_CAP];         // (i_slot << 16) | prev_slot for m1->m1 rows
__device__ int   g_chain2[BTq][NM_CAP];        // deep-chain subset (source itself chain at t-1)
__device__ unsigned char g_cls[BTq][NM_CAP];   // per-m1-row class: 0 plain, 1 chain, 2 m23-sourced
__device__ float g_Pc[Nq][Gq];                 // c_emb @ Wg
__device__ float g_Pn[Nq][Gq];                 // n_emb @ Wg
__device__ float g_co[BTq][NC_CAP][Gq];        // co at active c rows (slot order)
__device__ float g_no[BTq][NC_CAP][Gq];        // no at active nb rows (slot order)
__device__ float g_hm23[BTq][NM_CAP][Hq];      // tanh(P@v) — ONLY rows m1 at t+1 are written/read
__device__ float g_om23p2[2][BTq][Hq];         // om23 partial max per query-parity half
__device__ float g_hm1[BTq][NM_CAP][Hq];       // GRU outputs at m1 rows (slot = list1 index)
__device__ float g_om1p2[2][BTq][Hq];          // om1 partial max over NON-chain m1 rows, per half
__device__ float g_om1c[BTq][Hq];              // om1 max over depth-1 chain rows

// inline gi helper (rare chain rows only): gi = bi + co @ Wi at column h
__device__ __forceinline__ void gi3(const float* co_row, const float* Wi, const float* bi, int h,
                                    float& gr, float& gz, float& gn){
    gr = bi[h]; gz = bi[Hq + h]; gn = bi[2 * Hq + h];
    #pragma unroll
    for (int g = 0; g < Gq; ++g){
        float c = co_row[g];
        const float* w = Wi + g * H3q + h;
        gr += c * w[0];
        gz += c * w[Hq];
        gn += c * w[2 * Hq];
    }
}

// -------- per-phase LDS layouts, union'd (max = SmMid ~98 KB -> 1 block/CU, 256 co-resident) ----
struct SmCo {
    unsigned char cf[Nq], nf[Nq];
    short lc[NC_CAP], ln[NC_CAP];
    short act[NACT];
    int nc, nn;
    float Pact[NACT][Gq];
    float A[MTILE][NACT];
    short mrow[MTILE];
};
struct SmMid {
    unsigned char f1[Nq], f2[Nq], f3[Nq];
    short l1[NM_CAP], l23[NM_CAP];
    unsigned char wm[NMH];
    int n1, n23;
    float co23[NM_CAP][Gq];
    float qr[NM_CAP][Gq];
    float q[NMH][TAq + 1];
    float k[NM_CAP][TAq + 1];
    float s[NMH][NM_CAP + 1];
    float vv[NM_CAP][Hq];
    float hm[NMH][Hq];
};
struct SmG1 {
    short map1p[Nq], map23p[Nq];
    short l1[NM_CAP];
    unsigned char cls[NM_CAP];
    int m23l[NM_CAP];
    int nf23;
    float co1[NMH][Gq];
    float hb[Hq];
    float ghf[H3q];
    float gi[NMH][H3q];
};
struct SmG1b {
    unsigned char defer[NM_CAP];
    float co[Gq];
    float hb[Hq];
    float ghf[H3q];
    float cmax[Hq];
};
struct SmG2f {
    float co[Gq];
    float hb[Hq];
    float ghf[H3q];
    float outs[Tq][Hq];
    float wdc[Hq];
    float score[Tq];
    float pooled[Hq];
};
union SmU { SmCo co; SmMid mid; SmG1 g1; SmG1b g1b; SmG2f g2f; };

// -------- the fused pipeline: 6 phases, 5 grid syncs --------
__global__ __launch_bounds__(512) void k_fused(
        const float* code_x, const float* divided, const float* neighbors, const int* lens,
        const float* adj, const float* c_emb, const float* n_emb, const float* u_emb,
        const float* Wg, const float* bg, const float* Wi, const float* bi,
        const float* Wh, const float* bh, const float* Wq_, const float* bq_,
        const float* Wk_, const float* bk_, const float* Wv_, const float* bv_,
        const float* Wd_, const float* bd_, const float* ctx, const float* Wc_,
        const float* bc_, float* out){
    cg::grid_group grid = cg::this_grid();
    __shared__ SmU sm;
    int blk = blockIdx.x, tid = threadIdx.x;
    int wave = tid >> 6, lane = tid & 63;

    // ================= phase 0: pre (Pc = c_emb@Wg, Pn = n_emb@Wg) =================
    {
        int idx = blk * 512 + tid;           // 131072 threads, 65536 items
        if (idx < 65536){
            int which = idx >> 15;
            int r = (idx >> 5) & 1023;
            int g = idx & 31;
            const float* emb = which ? n_emb : c_emb;
            float acc = 0.f;
            for (int c = 0; c < Cq; ++c) acc += emb[r * Cq + c] * Wg[c * Gq + g];
            if (which) g_Pn[r][g] = acc; else g_Pc[r][g] = acc;
        }
    }
    grid.sync();

    // ================= phase 1: co/no (2 blocks per bt, odd/even m rows) =================
    {
        int bt = blk >> 1, half = blk & 1;
        for (int n = tid; n < Nq; n += 512){
            sm.co.cf[n] = (code_x[bt * Nq + n]    > 0.f) ? 1 : 0;
            sm.co.nf[n] = (neighbors[bt * Nq + n] > 0.f) ? 1 : 0;
        }
        __syncthreads();
        if (wave == 0){
            int base = 0;
            for (int start = 0; start < Nq; start += 64){
                int n = start + lane;
                int pred = sm.co.cf[n];
                unsigned long long mm = __ballot(pred != 0);
                int pos = base + (int)__popcll(mm & ((1ull << lane) - 1ull));
                if (pred && pos < NC_CAP) sm.co.lc[pos] = (short)n;
                base += (int)__popcll(mm);
            }
            if (lane == 0) sm.co.nc = min(base, NC_CAP);
        } else if (wave == 1){
            int base = 0;
            for (int start = 0; start < Nq; start += 64){
                int n = start + lane;
                int pred = sm.co.nf[n];
                unsigned long long mm = __ballot(pred != 0);
                int pos = base + (int)__popcll(mm & ((1ull << lane) - 1ull));
                if (pred && pos < NC_CAP) sm.co.ln[pos] = (short)n;
                base += (int)__popcll(mm);
            }
            if (lane == 0) sm.co.nn = min(base, NC_CAP);
        } else {
            if (half == 0) for (int n = tid - 128; n < Nq; n += 384) g_mapc[bt][n] = -1;
            else           for (int n = tid - 128; n < Nq; n += 384) g_mapn[bt][n] = -1;
        }
        __syncthreads();
        int nc = sm.co.nc, nn = sm.co.nn, total = nc + nn;
        for (int i = tid; i < total; i += 512) sm.co.act[i] = (i < nc) ? sm.co.lc[i] : sm.co.ln[i - nc];
        if (half == 0) for (int i = tid; i < nc; i += 512) g_mapc[bt][sm.co.lc[i]] = (short)i;
        else           for (int i = tid; i < nn; i += 512) g_mapn[bt][sm.co.ln[i]] = (short)i;
        __syncthreads();
        for (int idx = tid; idx < total * Gq; idx += 512){
            int i = idx >> 5, g = idx & 31;
            sm.co.Pact[i][g] = (i < nc) ? g_Pc[sm.co.act[i]][g] : g_Pn[sm.co.act[i]][g];
        }
        __syncthreads();
        int g = tid & 31, grp = tid >> 5;
        float bgv = bg[g];
        for (int rbase = half; rbase < total; rbase += 2 * MTILE){
            if (tid < MTILE){
                int r = rbase + 2 * tid;
                sm.co.mrow[tid] = (r < total) ? sm.co.act[r] : 0;
            }
            __syncthreads();
            int ntile = min(MTILE, (total - rbase + 1) / 2);
            for (int idx = tid; idx < ntile * total; idx += 512){
                int ti = idx / total, j = idx % total;
                sm.co.A[ti][j] = adj[(size_t)sm.co.mrow[ti] * Nq + sm.co.act[j]];
            }
            __syncthreads();
            if (grp < ntile){
                int r = rbase + 2 * grp;
                float agg = 0.f;
                #pragma unroll 4
                for (int j = 0; j < total; ++j) agg += sm.co.A[grp][j] * sm.co.Pact[j][g];
                float v = lrelu(sm.co.Pact[r][g] + agg + bgv);
                if (r < nc) g_co[bt][r][g]      = v;
                else        g_no[bt][r - nc][g] = v;
            }
            __syncthreads();
        }
    }
    grid.sync();

    // ================= phase 2: lists + attention (2 blocks per bt, query halves) =================
    {
        int bt = blk >> 1, half = blk & 1;
        int t = bt % Tq, btp = bt - 1;
        for (int idx = tid; idx < Nq * 3; idx += 512){
            float v = divided[(size_t)bt * Nq * 3 + idx];
            int n = idx / 3, c = idx - n * 3;
            unsigned char f = (v > 0.f) ? 1 : 0;
            if (c == 0) sm.mid.f1[n] = f;
            else if (c == 1) sm.mid.f2[n] = f;
            else sm.mid.f3[n] = f;
        }
        __syncthreads();
        if (wave == 0){
            int base = 0;
            for (int start = 0; start < Nq; start += 64){
                int n = start + lane;
                int pred = sm.mid.f1[n];
                unsigned long long mm = __ballot(pred != 0);
                int pos = base + (int)__popcll(mm & ((1ull << lane) - 1ull));
                if (pred && pos < NM_CAP) sm.mid.l1[pos] = (short)n;
                base += (int)__popcll(mm);
            }
            if (lane == 0) sm.mid.n1 = min(base, NM_CAP);
        } else if (wave == 1){
            int base = 0;
            for (int start = 0; start < Nq; start += 64){
                int n = start + lane;
                int m2 = sm.mid.f2[n], m3 = sm.mid.f3[n];
                int pred = m2 | m3;
                unsigned long long mm = __ballot(pred != 0);
                int pos = base + (int)__popcll(mm & ((1ull << lane) - 1ull));
                if (pred && pos < NM_CAP) sm.mid.l23[pos] = (short)(n | (m2 ? 0x400 : 0));
                base += (int)__popcll(mm);
            }
            if (lane == 0) sm.mid.n23 = min(base, NM_CAP);
        }
        __syncthreads();
        int n1 = sm.mid.n1, n23 = sm.mid.n23;
        if (half == 0){
            for (int i = tid; i < n1;  i += 512) g_list1[bt][i]  = sm.mid.l1[i];
            for (int i = tid; i < n23; i += 512) g_list23[bt][i] = sm.mid.l23[i];
            if (tid == 0){ g_n1[bt] = n1; g_n23[bt] = n23; }
        }
        if (t != 0 && n23 != 0){                 // block-uniform guard (no return: must reach grid.sync)
            int nMy = (n23 > half) ? ((n23 - half + 1) >> 1) : 0;
            for (int il = tid; il < nMy; il += 512){
                int row = sm.mid.l23[2 * il + half] & 1023;
                unsigned char wm = 0;
                if (t < Tq - 1) wm = (divided[((size_t)(bt + 1) * Nq + row) * 3] > 0.f) ? 1 : 0;
                sm.mid.wm[il] = wm;
            }
            for (int idx = tid; idx < n23 * Gq; idx += 512){
                int i = idx >> 5, g = idx & 31;
                sm.mid.co23[i][g] = g_co[bt][g_mapc[bt][sm.mid.l23[i] & 1023]][g];
            }
            for (int idx = tid; idx < n23 * Gq; idx += 512){
                int i = idx >> 5, g = idx & 31;
                int e = sm.mid.l23[i], row = e & 1023;
                float qv;
                if (e & 0x400){
                    int slot = g_mapn[btp][row];
                    qv = (slot >= 0) ? g_no[btp][slot][g] : lrelu(bg[g]);
                } else {
                    qv = u_emb[row * Gq + g];
                }
                sm.mid.qr[i][g] = qv;
            }
            __syncthreads();
            for (int idx = tid; idx < n23 * TAq; idx += 512){
                int i = idx >> 5, a = idx & 31;
                float acck = bk_[a];
                #pragma unroll
                for (int g = 0; g < Gq; ++g) acck += sm.mid.co23[i][g] * Wk_[g * TAq + a];
                sm.mid.k[i][a] = acck;
            }
            for (int idx = tid; idx < nMy * TAq; idx += 512){
                int il = idx >> 5, a = idx & 31;
                int i = 2 * il + half;
                float accq = bq_[a];
                #pragma unroll
                for (int g = 0; g < Gq; ++g) accq += sm.mid.qr[i][g] * Wq_[g * TAq + a];
                sm.mid.q[il][a] = accq;
            }
            for (int idx = tid; idx < n23 * Hq; idx += 512){
                int i = idx / Hq, h = idx % Hq;
                float acc = bv_[h];
                #pragma unroll
                for (int g = 0; g < Gq; ++g) acc += sm.mid.qr[i][g] * Wv_[g * Hq + h];
                sm.mid.vv[i][h] = acc;
            }
            __syncthreads();
            const float scale = 0.17677669529663687f;   // 1/sqrt(32)
            for (int idx = tid; idx < nMy * n23; idx += 512){
                int il = idx / n23, j = idx % n23;
                float acc = 0.f;
                #pragma unroll
                for (int a = 0; a < TAq; ++a) acc += sm.mid.q[il][a] * sm.mid.k[j][a];
                sm.mid.s[il][j] = acc * scale;
            }
            __syncthreads();
            for (int il = tid; il < nMy; il += 512){
                float mx = -1e30f;
                for (int j = 0; j < n23; ++j) mx = fmaxf(mx, sm.mid.s[il][j]);
                float sum = 0.f;
                for (int j = 0; j < n23; ++j){ float e = expf(sm.mid.s[il][j] - mx); sm.mid.s[il][j] = e; sum += e; }
                float inv = 1.f / sum;
                for (int j = 0; j < n23; ++j) sm.mid.s[il][j] *= inv;
            }
            __syncthreads();
            for (int idx = tid; idx < nMy * Hq; idx += 512){
                int il = idx / Hq, h = idx % Hq;
                float acc = 0.f;
                for (int j = 0; j < n23; ++j) acc += sm.mid.s[il][j] * sm.mid.vv[j][h];
                sm.mid.hm[il][h] = tanhf(acc);
            }
            __syncthreads();
            for (int idx = tid; idx < nMy * Hq; idx += 512){
                int il = idx / Hq, h = idx % Hq;
                if (sm.mid.wm[il]) g_hm23[bt][2 * il + half][h] = sm.mid.hm[il][h];
            }
            for (int h = tid; h < Hq; h += 512){
                float mx = -1e30f;
                for (int il = 0; il < nMy; ++il) mx = fmaxf(mx, sm.mid.hm[il][h]);
                g_om23p2[half][bt][h] = mx;
            }
        }
    }
    grid.sync();

    // ================= phase 3: gru1 (2 blocks per bt, m1-row halves) =================
    {
        int bt = blk >> 1, half = blk & 1;
        int t = bt % Tq, btp = bt - 1;
        int n1 = g_n1[bt];
        int nMy = (n1 > half) ? ((n1 - half + 1) >> 1) : 0;
        for (int n = tid; n < Nq; n += 512){ sm.g1.map1p[n] = -1; sm.g1.map23p[n] = -1; }
        for (int i = tid; i < n1; i += 512) sm.g1.l1[i] = g_list1[bt][i];
        __syncthreads();
        if (t >= 1){
            int n1p = g_n1[btp];
            for (int i = tid; i < n1p; i += 512) sm.g1.map1p[g_list1[btp][i]] = (short)i;
            if (t >= 2){
                int n23p = g_n23[btp];
                for (int i = tid; i < n23p; i += 512) sm.g1.map23p[g_list23[btp][i] & 1023] = (short)i;
            }
        }
        __syncthreads();
        if (tid < 64){
            int i = tid;
            int cls = 0, sp = -1;
            if (i < n1 && t >= 1){
                int row = sm.g1.l1[i];
                if (sm.g1.map1p[row] >= 0){ cls = 1; sp = sm.g1.map1p[row]; }
                else if (t >= 2 && sm.g1.map23p[row] >= 0){ cls = 2; sp = sm.g1.map23p[row]; }
            }
            if (i < n1) sm.g1.cls[i] = (unsigned char)cls;
            if (half == 0 && i < n1) g_cls[bt][i] = (unsigned char)cls;
            unsigned long long mch = __ballot(cls == 1);
            unsigned long long m23 = __ballot(cls == 2 && (i & 1) == half);
            int pch = (int)__popcll(mch & ((1ull << i) - 1ull));
            int p23 = (int)__popcll(m23 & ((1ull << i) - 1ull));
            if (half == 0 && cls == 1) g_chain[bt][pch] = (i << 16) | sp;
            if (cls == 2 && (i & 1) == half) sm.g1.m23l[p23] = (i << 16) | sp;
            if (i == 0){
                sm.g1.nf23 = (int)__popcll(m23);
                if (half == 0) g_nchain[bt] = (int)__popcll(mch);
            }
        }
        for (int idx = tid; idx < nMy * Gq; idx += 512){
            int il = idx >> 5, g = idx & 31;
            sm.g1.co1[il][g] = g_co[bt][g_mapc[bt][sm.g1.l1[2 * il + half]]][g];
        }
        __syncthreads();
        if (tid < H3q){
            float wcol[Gq];
            #pragma unroll
            for (int g = 0; g < Gq; ++g) wcol[g] = Wi[g * H3q + tid];
            float bij = bi[tid];
            for (int il = 0; il < nMy; ++il){
                float acc = bij;
                #pragma unroll
                for (int g = 0; g < Gq; ++g) acc += sm.g1.co1[il][g] * wcol[g];
                sm.g1.gi[il][tid] = acc;
            }
        }
        __syncthreads();
        for (int idx = tid; idx < nMy * Hq; idx += 512){
            int il = idx / Hq, h = idx % Hq;
            int i = 2 * il + half;
            if (sm.g1.cls[i] != 0) continue;
            float gr = sm.g1.gi[il][h], gz = sm.g1.gi[il][Hq + h], gn = sm.g1.gi[il][2 * Hq + h];
            float r  = sigm(gr + bh[h]);
            float z  = sigm(gz + bh[Hq + h]);
            float ng = tanhf(gn + r * bh[2 * Hq + h]);
            sm.g1.gi[il][h] = (1.f - z) * ng;
        }
        __syncthreads();
        int nf23 = sm.g1.nf23;
        for (int f = 0; f < nf23; ++f){
            int pk = sm.g1.m23l[f]; int i = pk >> 16, sp = pk & 0xffff;
            int il = i >> 1;
            for (int h = tid; h < Hq; h += 512) sm.g1.hb[h] = g_hm23[btp][sp][h];
            __syncthreads();
            for (int j = tid; j < H3q; j += 512){
                float acc = bh[j];
                for (int k2 = 0; k2 < Hq; ++k2) acc += sm.g1.hb[k2] * Wh[k2 * H3q + j];
                sm.g1.ghf[j] = acc;
            }
            __syncthreads();
            for (int h = tid; h < Hq; h += 512){
                float gr = sm.g1.gi[il][h], gz = sm.g1.gi[il][Hq + h], gn = sm.g1.gi[il][2 * Hq + h];
                float r  = sigm(gr + sm.g1.ghf[h]);
                float z  = sigm(gz + sm.g1.ghf[Hq + h]);
                float ng = tanhf(gn + r * sm.g1.ghf[2 * Hq + h]);
                sm.g1.gi[il][h] = (1.f - z) * ng + z * sm.g1.hb[h];
            }
            __syncthreads();
        }
        for (int idx = tid; idx < nMy * Hq; idx += 512){
            int il = idx / Hq, h = idx % Hq;
            int i = 2 * il + half;
            if (sm.g1.cls[i] != 1) g_hm1[bt][i][h] = sm.g1.gi[il][h];
        }
        for (int h = tid; h < Hq; h += 512){
            float mx = -1e30f;
            for (int il = 0; il < nMy; ++il)
                if (sm.g1.cls[2 * il + half] != 1) mx = fmaxf(mx, sm.g1.gi[il][h]);
            g_om1p2[half][bt][h] = mx;
        }
    }
    grid.sync();

    // ================= phase 4: gru1b (128 blocks; depth-1 chain rows) =================
    if (blk < BTq){
        int bt = blk;
        int t = bt % Tq, btp = bt - 1;
        int nch = (t > 0) ? g_nchain[bt] : 0;
        for (int h = tid; h < Hq; h += 512) sm.g1b.cmax[h] = -1e30f;
        if (tid < 64){
            int c = tid;
            int defer = 0;
            if (c < nch){
                int sp = g_chain[bt][c] & 0xffff;
                defer = (g_cls[btp][sp] == 1) ? 1 : 0;
                sm.g1b.defer[c] = (unsigned char)defer;
            }
            unsigned long long md = __ballot((c < nch) && defer);
            int pos = (int)__popcll(md & ((1ull << c) - 1ull));
            if ((c < nch) && defer) g_chain2[bt][pos] = g_chain[bt][c];
            if (c == 0) g_nchain2[bt] = (int)__popcll(md);
        }
        __syncthreads();
        for (int c = 0; c < nch; ++c){
            if (sm.g1b.defer[c]) continue;           // block-uniform
            int pk = g_chain[bt][c]; int i = pk >> 16, sp = pk & 0xffff;
            if (tid < Gq) sm.g1b.co[tid] = g_co[bt][g_mapc[bt][g_list1[bt][i]]][tid];
            for (int h = tid; h < Hq; h += 512) sm.g1b.hb[h] = g_hm1[btp][sp][h];
            __syncthreads();
            for (int j = tid; j < H3q; j += 512){
                float acc = bh[j];
                for (int k2 = 0; k2 < Hq; ++k2) acc += sm.g1b.hb[k2] * Wh[k2 * H3q + j];
                sm.g1b.ghf[j] = acc;
            }
            __syncthreads();
            for (int h = tid; h < Hq; h += 512){
                float gr, gz, gn;
                gi3(sm.g1b.co, Wi, bi, h, gr, gz, gn);
                float r  = sigm(gr + sm.g1b.ghf[h]);
                float z  = sigm(gz + sm.g1b.ghf[Hq + h]);
                float ng = tanhf(gn + r * sm.g1b.ghf[2 * Hq + h]);
                float v  = (1.f - z) * ng + z * sm.g1b.hb[h];
                g_hm1[bt][i][h] = v;
                sm.g1b.cmax[h] = fmaxf(sm.g1b.cmax[h], v);
            }
            __syncthreads();
        }
        for (int h = tid; h < Hq; h += 512) g_om1c[bt][h] = sm.g1b.cmax[h];
    }
    grid.sync();

    // ================= phase 5: gru2f (8 blocks; deep-chain + outs + attention + classifier) ====
    if (blk < Bq){
        int b = blk;
        for (int t = 1; t < Tq; ++t){
            int bt = b * Tq + t, btp = bt - 1;
            int nch2 = g_nchain2[bt];
            for (int c = 0; c < nch2; ++c){
                int pk = g_chain2[bt][c]; int i = pk >> 16, sp = pk & 0xffff;
                if (tid < Gq) sm.g2f.co[tid] = g_co[bt][g_mapc[bt][g_list1[bt][i]]][tid];
                for (int h = tid; h < Hq; h += 512) sm.g2f.hb[h] = g_hm1[btp][sp][h];
                __syncthreads();
                for (int j = tid; j < H3q; j += 512){
                    float acc = bh[j];
                    for (int k2 = 0; k2 < Hq; ++k2) acc += sm.g2f.hb[k2] * Wh[k2 * H3q + j];
                    sm.g2f.ghf[j] = acc;
                }
                __syncthreads();
                for (int h = tid; h < Hq; h += 512){
                    float gr, gz, gn;
                    gi3(sm.g2f.co, Wi, bi, h, gr, gz, gn);
                    float r  = sigm(gr + sm.g2f.ghf[h]);
                    float z  = sigm(gz + sm.g2f.ghf[Hq + h]);
                    float ng = tanhf(gn + r * sm.g2f.ghf[2 * Hq + h]);
                    g_hm1[bt][i][h] = (1.f - z) * ng + z * sm.g2f.hb[h];
                }
                __syncthreads();
            }
        }
        for (int idx = tid; idx < Tq * Hq; idx += 512){
            int t = idx / Hq, h = idx % Hq;
            int bt = b * Tq + t;
            int n1 = g_n1[bt], n23 = (t > 0) ? g_n23[bt] : 0;
            float o = 0.f;
            if (n1 > 0){
                float mx = fmaxf(fmaxf(g_om1p2[0][bt][h], g_om1p2[1][bt][h]), g_om1c[bt][h]);
                int nd = (t > 0) ? g_nchain2[bt] : 0;
                for (int c = 0; c < nd; ++c){
                    int i = g_chain2[bt][c] >> 16;
                    mx = fmaxf(mx, g_hm1[bt][i][h]);
                }
                o = mx;
            }
            if (n23 > 0) o += fmaxf(g_om23p2[0][bt][h], g_om23p2[1][bt][h]);
            sm.g2f.outs[t][h] = o;
        }
        for (int h = tid; h < Hq; h += 512){
            float acc = 0.f;
            for (int d = 0; d < 32; ++d) acc += Wd_[h * 32 + d] * ctx[d];
            sm.g2f.wdc[h] = acc;
        }
        __syncthreads();
        int len = lens[b];
        if (tid < Tq){
            int t = tid;
            float acc = 0.f;
            for (int d = 0; d < 32; ++d) acc += bd_[d] * ctx[d];
            for (int h = 0; h < Hq; ++h) acc += sm.g2f.outs[t][h] * sm.g2f.wdc[h];
            sm.g2f.score[t] = (t < len) ? acc : -1e30f;
        }
        __syncthreads();
        if (tid == 0){
            float mx = -1e30f;
            for (int t = 0; t < Tq; ++t) mx = fmaxf(mx, sm.g2f.score[t]);
            float sum = 0.f;
            for (int t = 0; t < Tq; ++t){ float e = expf(sm.g2f.score[t] - mx); sm.g2f.score[t] = e; sum += e; }
            float inv = 1.f / sum;
            for (int t = 0; t < Tq; ++t) sm.g2f.score[t] *= inv;
        }
        __syncthreads();
        for (int h = tid; h < Hq; h += 512){
            float acc = 0.f;
            for (int t = 0; t < Tq; ++t) acc += sm.g2f.score[t] * sm.g2f.outs[t][h];
            sm.g2f.pooled[h] = acc;
        }
        __syncthreads();
        for (int o = tid; o < OUTq; o += 512){
            float acc = bc_[o];
            for (int h = 0; h < Hq; ++h) acc += sm.g2f.pooled[h] * Wc_[h * OUTq + o];
            out[b * OUTq + o] = sigm(acc);
        }
    }
}

extern "C" void kernel_launch(void* const* d_in, const int* in_sizes, int n_in,
                              void* d_out, int out_size, void* d_ws, size_t ws_size,
                              hipStream_t stream){
    const float* code_x    = (const float*)d_in[0];
    const float* divided   = (const float*)d_in[1];
    const float* neighbors = (const float*)d_in[2];
    const int*   lens      = (const int*)  d_in[3];
    const float* adj       = (const float*)d_in[4];
    const float* c_emb     = (const float*)d_in[5];
    const float* n_emb     = (const float*)d_in[6];
    const float* u_emb     = (const float*)d_in[7];
    const float* Wg        = (const float*)d_in[8];
    const float* bg        = (const float*)d_in[9];
    const float* Wi        = (const float*)d_in[10];
    const float* bi        = (const float*)d_in[11];
    const float* Wh        = (const float*)d_in[12];
    const float* bh        = (const float*)d_in[13];
    const float* Wq_       = (const float*)d_in[14];
    const float* bq_       = (const float*)d_in[15];
    const float* Wk_       = (const float*)d_in[16];
    const float* bk_       = (const float*)d_in[17];
    const float* Wv_       = (const float*)d_in[18];
    const float* bv_       = (const float*)d_in[19];
    const float* Wd_       = (const float*)d_in[20];
    const float* bd_       = (const float*)d_in[21];
    const float* ctx       = (const float*)d_in[22];
    const float* Wc_       = (const float*)d_in[23];
    const float* bc_       = (const float*)d_in[24];
    float* out = (float*)d_out;

    void* args[] = {
        (void*)&code_x, (void*)&divided, (void*)&neighbors, (void*)&lens,
        (void*)&adj, (void*)&c_emb, (void*)&n_emb, (void*)&u_emb,
        (void*)&Wg, (void*)&bg, (void*)&Wi, (void*)&bi,
        (void*)&Wh, (void*)&bh, (void*)&Wq_, (void*)&bq_,
        (void*)&Wk_, (void*)&bk_, (void*)&Wv_, (void*)&bv_,
        (void*)&Wd_, (void*)&bd_, (void*)&ctx, (void*)&Wc_,
        (void*)&bc_, (void*)&out
    };
    hipLaunchCooperativeKernel((const void*)k_fused, dim3(2 * BTq), dim3(512),
                               args, 0, stream);
}

// Round 18
// 258.529 us; speedup vs baseline: 1.6009x; 1.6009x over previous
//
#include <hip/hip_runtime.h>
#include <hip/hip_bf16.h>

#define Bq   8
#define Tq   16
#define Nq   1024
#define Cq   48
#define Gq   32
#define Hq   150
#define H3q  450
#define TAq  32
#define OUTq 1024
#define BTq  128

#define NC_CAP 128   // active code / neighbor rows per (b,t): Binom(1024,.06) mean 61 sd 7.6
#define NM_CAP 64    // m1 / m23 rows per (b,t): Binom(1024,.03) mean 30.7 sd 5.5
#define NACT   (2 * NC_CAP)
#define MTILE  16
#define NMH    (NM_CAP / 2)

__device__ __forceinline__ float lrelu(float x){ return x > 0.f ? x : 0.01f * x; }
__device__ __forceinline__ float sigm(float x){ return 1.f / (1.f + expf(-x)); }

// -------- device-global scratch (everything read is written earlier in the same call) --------
__device__ int   g_n1[BTq], g_n23[BTq], g_nchain[BTq], g_nchain2[BTq];
__device__ short g_list1[BTq][NM_CAP];
__device__ short g_list23[BTq][NM_CAP];        // row | (m2 ? 0x400 : 0), ascending row order
__device__ short g_mapc[BTq][Nq];              // row -> slot in c-list (-1 if inactive)
__device__ short g_mapn[BTq][Nq];              // row -> slot in nb-list (-1 if inactive)
__device__ int   g_chain[BTq][NM_CAP];         // (i_slot << 16) | prev_slot for m1->m1 rows
__device__ int   g_chain2[BTq][NM_CAP];        // deep-chain subset (source itself chain at t-1)
__device__ unsigned char g_cls[BTq][NM_CAP];   // per-m1-row class: 0 plain, 1 chain, 2 m23-sourced
__device__ float g_Pc[Nq][Gq];                 // c_emb @ Wg
__device__ float g_Pn[Nq][Gq];                 // n_emb @ Wg
__device__ float g_co[BTq][NC_CAP][Gq];        // co at active c rows (slot order)
__device__ float g_no[BTq][NC_CAP][Gq];        // no at active nb rows (slot order)
__device__ float g_hm23[BTq][NM_CAP][Hq];      // tanh(P@v) — ONLY rows m1 at t+1 are written/read
__device__ float g_om23p2[2][BTq][Hq];         // om23 partial max per query-parity half
__device__ float g_hm1[BTq][NM_CAP][Hq];       // GRU outputs at m1 rows (slot = list1 index)
__device__ float g_om1p2[2][BTq][Hq];          // om1 partial max over NON-chain m1 rows, per half
__device__ float g_om1c[BTq][Hq];              // om1 max over depth-1 chain rows (k_gru1b)

// inline gi helper (used ONLY for rare chain rows, ~1/block): gi = bi + co @ Wi at column h
__device__ __forceinline__ void gi3(const float* co_row, const float* Wi, const float* bi, int h,
                                    float& gr, float& gz, float& gn){
    gr = bi[h]; gz = bi[Hq + h]; gn = bi[2 * Hq + h];
    #pragma unroll
    for (int g = 0; g < Gq; ++g){
        float c = co_row[g];
        const float* w = Wi + g * H3q + h;
        gr += c * w[0];
        gz += c * w[Hq];
        gn += c * w[2 * Hq];
    }
}

// -------- K_pre: project embeddings through Wg once (linear: (adj@ce)@Wg = adj@(ce@Wg)) --------
__global__ __launch_bounds__(256) void k_pre(const float* c_emb, const float* n_emb, const float* Wg){
    int idx   = blockIdx.x * 256 + threadIdx.x;   // 65536 threads exactly
    int which = idx >> 15;
    int r     = (idx >> 5) & 1023;
    int g     = idx & 31;
    const float* emb = which ? n_emb : c_emb;
    float acc = 0.f;
    for (int c = 0; c < Cq; ++c)
        acc += emb[r * Cq + c] * Wg[c * Gq + g];
    if (which) g_Pn[r][g] = acc; else g_Pc[r][g] = acc;
}

// -------- K_co: sparse co/no as tiled gathered-GEMM. 2 blocks per (b,t) (odd/even m rows).
// Activity flags staged to LDS first; ballot runs over LDS (no serial global chain). --------
__global__ __launch_bounds__(512) void k_co(const float* code_x, const float* neighbors,
                                            const float* adj, const float* bg){
    int bt = blockIdx.x >> 1, half = blockIdx.x & 1, tid = threadIdx.x;
    __shared__ unsigned char cf_s[Nq], nf_s[Nq];   // 2 KB staged activity flags
    __shared__ short lc_s[NC_CAP], ln_s[NC_CAP];
    __shared__ short act_s[NACT];
    __shared__ int nc_s, nn_s;
    __shared__ float Pact_s[NACT][Gq];           // 32 KB
    __shared__ float A_s[MTILE][NACT];           // 16 KB
    __shared__ short mrow_s[MTILE];
    int wave = tid >> 6, lane = tid & 63;

    // coalesced flag staging (removes 16-iter serial global-latency ballot chain)
    for (int n = tid; n < Nq; n += 512){
        cf_s[n] = (code_x[bt * Nq + n]    > 0.f) ? 1 : 0;
        nf_s[n] = (neighbors[bt * Nq + n] > 0.f) ? 1 : 0;
    }
    __syncthreads();
    if (wave == 0){           // compact c-active rows (ballot over LDS flags)
        int base = 0;
        for (int start = 0; start < Nq; start += 64){
            int n = start + lane;
            int pred = cf_s[n];
            unsigned long long mm = __ballot(pred != 0);
            int pos = base + (int)__popcll(mm & ((1ull << lane) - 1ull));
            if (pred && pos < NC_CAP) lc_s[pos] = (short)n;
            base += (int)__popcll(mm);
        }
        if (lane == 0) nc_s = min(base, NC_CAP);
    } else if (wave == 1){    // compact nb-active rows
        int base = 0;
        for (int start = 0; start < Nq; start += 64){
            int n = start + lane;
            int pred = nf_s[n];
            unsigned long long mm = __ballot(pred != 0);
            int pos = base + (int)__popcll(mm & ((1ull << lane) - 1ull));
            if (pred && pos < NC_CAP) ln_s[pos] = (short)n;
            base += (int)__popcll(mm);
        }
        if (lane == 0) nn_s = min(base, NC_CAP);
    } else {                  // clear map half (384 threads, 1024 entries)
        if (half == 0) for (int n = tid - 128; n < Nq; n += 384) g_mapc[bt][n] = -1;
        else           for (int n = tid - 128; n < Nq; n += 384) g_mapn[bt][n] = -1;
    }
    __syncthreads();
    int nc = nc_s, nn = nn_s, total = nc + nn;

    for (int i = tid; i < total; i += 512) act_s[i] = (i < nc) ? lc_s[i] : ln_s[i - nc];
    if (half == 0) for (int i = tid; i < nc; i += 512) g_mapc[bt][lc_s[i]] = (short)i;
    else           for (int i = tid; i < nn; i += 512) g_mapn[bt][ln_s[i]] = (short)i;
    __syncthreads();

    for (int idx = tid; idx < total * Gq; idx += 512){
        int i = idx >> 5, g = idx & 31;
        Pact_s[i][g] = (i < nc) ? g_Pc[act_s[i]][g] : g_Pn[act_s[i]][g];
    }
    __syncthreads();

    int g = tid & 31, grp = tid >> 5;
    float bgv = bg[g];
    for (int rbase = half; rbase < total; rbase += 2 * MTILE){
        if (tid < MTILE){
            int r = rbase + 2 * tid;
            mrow_s[tid] = (r < total) ? act_s[r] : 0;
        }
        __syncthreads();
        int ntile = min(MTILE, (total - rbase + 1) / 2);
        for (int idx = tid; idx < ntile * total; idx += 512){
            int ti = idx / total, j = idx % total;
            A_s[ti][j] = adj[(size_t)mrow_s[ti] * Nq + act_s[j]];
        }
        __syncthreads();
        if (grp < ntile){
            int r = rbase + 2 * grp;
            float agg = 0.f;
            #pragma unroll 4
            for (int j = 0; j < total; ++j) agg += A_s[grp][j] * Pact_s[j][g];
            float v = lrelu(Pact_s[r][g] + agg + bgv);
            if (r < nc) g_co[bt][r][g]      = v;
            else        g_no[bt][r - nc][g] = v;
        }
        __syncthreads();
    }
}

// -------- K_mid (2 blocks per (b,t), odd/even query rows): lists + attention in LDS --------
__global__ __launch_bounds__(512) void k_mid(const float* divided, const float* u_emb,
                                             const float* Wk, const float* bk,
                                             const float* Wq_, const float* bq_,
                                             const float* Wv_, const float* bv_,
                                             const float* bg){
    int bt = blockIdx.x >> 1, half = blockIdx.x & 1, tid = threadIdx.x;
    int t = bt % Tq, btp = bt - 1;
    __shared__ unsigned char f1_s[Nq], f2_s[Nq], f3_s[Nq];   // 3 KB staged divided flags
    __shared__ short l1_s[NM_CAP], l23_s[NM_CAP];
    __shared__ unsigned char wm_s[NMH];
    __shared__ int n1_s, n23_s;
    __shared__ float co23_s[NM_CAP][Gq];         // 8 KB (all keys)
    __shared__ float qr_s[NM_CAP][Gq];           // 8 KB (all rows; v needs all)
    __shared__ float q_s[NMH][TAq + 1];          // my queries
    __shared__ float k_s[NM_CAP][TAq + 1];       // all keys
    __shared__ float s_s[NMH][NM_CAP + 1];       // my scores
    __shared__ float vv_s[NM_CAP][Hq];           // 38.4 KB (all values)
    __shared__ float hm_s[NMH][Hq];              // 19.2 KB (my outputs)
    int wave = tid >> 6, lane = tid & 63;

    // stage divided flags coalesced (removes serial global-latency ballot chain)
    for (int idx = tid; idx < Nq * 3; idx += 512){
        float v = divided[(size_t)bt * Nq * 3 + idx];
        int n = idx / 3, c = idx - n * 3;
        unsigned char f = (v > 0.f) ? 1 : 0;
        if (c == 0) f1_s[n] = f;
        else if (c == 1) f2_s[n] = f;
        else f3_s[n] = f;
    }
    __syncthreads();
    if (wave == 0){           // m1 list (ballot over LDS flags)
        int base = 0;
        for (int start = 0; start < Nq; start += 64){
            int n = start + lane;
            int pred = f1_s[n];
            unsigned long long mm = __ballot(pred != 0);
            int pos = base + (int)__popcll(mm & ((1ull << lane) - 1ull));
            if (pred && pos < NM_CAP) l1_s[pos] = (short)n;
            base += (int)__popcll(mm);
        }
        if (lane == 0) n1_s = min(base, NM_CAP);
    } else if (wave == 1){    // m23 list with m2 tag
        int base = 0;
        for (int start = 0; start < Nq; start += 64){
            int n = start + lane;
            int m2 = f2_s[n], m3 = f3_s[n];
            int pred = m2 | m3;
            unsigned long long mm = __ballot(pred != 0);
            int pos = base + (int)__popcll(mm & ((1ull << lane) - 1ull));
            if (pred && pos < NM_CAP) l23_s[pos] = (short)(n | (m2 ? 0x400 : 0));
            base += (int)__popcll(mm);
        }
        if (lane == 0) n23_s = min(base, NM_CAP);
    }
    __syncthreads();
    int n1 = n1_s, n23 = n23_s;
    if (half == 0){
        for (int i = tid; i < n1;  i += 512) g_list1[bt][i]  = l1_s[i];
        for (int i = tid; i < n23; i += 512) g_list23[bt][i] = l23_s[i];
        if (tid == 0){ g_n1[bt] = n1; g_n23[bt] = n23; }
    }
    if (t == 0 || n23 == 0) return;   // block-uniform; attention applies only at t>=1
    int nMy = (n23 > half) ? ((n23 - half + 1) >> 1) : 0;   // queries i with (i&1)==half

    // hm23 row is read downstream ONLY if its row is m1 at t+1 (k_gru1's m23-sourced GRU)
    for (int il = tid; il < nMy; il += 512){
        int row = l23_s[2 * il + half] & 1023;
        unsigned char wm = 0;
        if (t < Tq - 1) wm = (divided[((size_t)(bt + 1) * Nq + row) * 3] > 0.f) ? 1 : 0;
        wm_s[il] = wm;
    }
    for (int idx = tid; idx < n23 * Gq; idx += 512){
        int i = idx >> 5, g = idx & 31;
        co23_s[i][g] = g_co[bt][g_mapc[bt][l23_s[i] & 1023]][g];
    }
    for (int idx = tid; idx < n23 * Gq; idx += 512){
        int i = idx >> 5, g = idx & 31;
        int e = l23_s[i], row = e & 1023;
        float qv;
        if (e & 0x400){
            int slot = g_mapn[btp][row];
            qv = (slot >= 0) ? g_no[btp][slot][g] : lrelu(bg[g]);
        } else {
            qv = u_emb[row * Gq + g];
        }
        qr_s[i][g] = qv;
    }
    __syncthreads();
    // k for ALL keys; q for MY queries; v for ALL rows
    for (int idx = tid; idx < n23 * TAq; idx += 512){
        int i = idx >> 5, a = idx & 31;
        float acck = bk[a];
        #pragma unroll
        for (int g = 0; g < Gq; ++g) acck += co23_s[i][g] * Wk[g * TAq + a];
        k_s[i][a] = acck;
    }
    for (int idx = tid; idx < nMy * TAq; idx += 512){
        int il = idx >> 5, a = idx & 31;
        int i = 2 * il + half;
        float accq = bq_[a];
        #pragma unroll
        for (int g = 0; g < Gq; ++g) accq += qr_s[i][g] * Wq_[g * TAq + a];
        q_s[il][a] = accq;
    }
    for (int idx = tid; idx < n23 * Hq; idx += 512){
        int i = idx / Hq, h = idx % Hq;
        float acc = bv_[h];
        #pragma unroll
        for (int g = 0; g < Gq; ++g) acc += qr_s[i][g] * Wv_[g * Hq + h];
        vv_s[i][h] = acc;
    }
    __syncthreads();

    const float scale = 0.17677669529663687f;   // 1/sqrt(32)
    for (int idx = tid; idx < nMy * n23; idx += 512){
        int il = idx / n23, j = idx % n23;
        float acc = 0.f;
        #pragma unroll
        for (int a = 0; a < TAq; ++a) acc += q_s[il][a] * k_s[j][a];
        s_s[il][j] = acc * scale;
    }
    __syncthreads();
    for (int il = tid; il < nMy; il += 512){     // per-query softmax over the m23 key set
        float mx = -1e30f;
        for (int j = 0; j < n23; ++j) mx = fmaxf(mx, s_s[il][j]);
        float sum = 0.f;
        for (int j = 0; j < n23; ++j){ float e = expf(s_s[il][j] - mx); s_s[il][j] = e; sum += e; }
        float inv = 1.f / sum;
        for (int j = 0; j < n23; ++j) s_s[il][j] *= inv;
    }
    __syncthreads();
    for (int idx = tid; idx < nMy * Hq; idx += 512){
        int il = idx / Hq, h = idx % Hq;
        float acc = 0.f;
        for (int j = 0; j < n23; ++j) acc += s_s[il][j] * vv_s[j][h];
        hm_s[il][h] = tanhf(acc);
    }
    __syncthreads();
    for (int idx = tid; idx < nMy * Hq; idx += 512){   // spill only rows k_gru1 will read
        int il = idx / Hq, h = idx % Hq;
        if (wm_s[il]) g_hm23[bt][2 * il + half][h] = hm_s[il][h];
    }
    for (int h = tid; h < Hq; h += 512){
        float mx = -1e30f;
        for (int il = 0; il < nMy; ++il) mx = fmaxf(mx, hm_s[il][h]);
        g_om23p2[half][bt][h] = mx;
    }
}

// -------- K_gru1 (2 blocks per (b,t), odd/even m1 rows): coop gi in LDS, GRU in place --------
__global__ __launch_bounds__(512) void k_gru1(const float* Wi, const float* bi,
                                              const float* Wh, const float* bh){
    int bt = blockIdx.x >> 1, half = blockIdx.x & 1, tid = threadIdx.x;
    int t = bt % Tq, btp = bt - 1;
    __shared__ short map1p[Nq], map23p[Nq];      // 4 KB
    __shared__ short l1_s[NM_CAP];
    __shared__ unsigned char cls_s[NM_CAP];      // 0=plain, 1=chain, 2=m23-sourced (all rows)
    __shared__ int m23l_s[NM_CAP];               // my half's (i<<16)|prev_slot
    __shared__ int nf23_s;
    __shared__ float co1_s[NMH][Gq];             // 4 KB (my rows, local index il = i>>1)
    __shared__ float hb_s[Hq];
    __shared__ float ghf_s[H3q];
    __shared__ float gi_s[NMH][H3q];             // 57.6 KB; cols [0,Hq) overwritten with hm1
    int n1 = g_n1[bt];
    int nMy = (n1 > half) ? ((n1 - half + 1) >> 1) : 0;   // rows i with (i&1)==half
    for (int n = tid; n < Nq; n += 512){ map1p[n] = -1; map23p[n] = -1; }
    for (int i = tid; i < n1; i += 512) l1_s[i] = g_list1[bt][i];
    __syncthreads();
    if (t >= 1){
        int n1p = g_n1[btp];
        for (int i = tid; i < n1p; i += 512) map1p[g_list1[btp][i]] = (short)i;
        if (t >= 2){
            int n23p = g_n23[btp];
            for (int i = tid; i < n23p; i += 512) map23p[g_list23[btp][i] & 1023] = (short)i;
        }
    }
    __syncthreads();
    if (tid < 64){                                // single wave: classify + ballot-compact
        int i = tid;
        int cls = 0, sp = -1;
        if (i < n1 && t >= 1){
            int row = l1_s[i];
            if (map1p[row] >= 0){ cls = 1; sp = map1p[row]; }
            else if (t >= 2 && map23p[row] >= 0){ cls = 2; sp = map23p[row]; }
        }
        if (i < n1) cls_s[i] = (unsigned char)cls;
        if (half == 0 && i < n1) g_cls[bt][i] = (unsigned char)cls;
        unsigned long long mch = __ballot(cls == 1);
        unsigned long long m23 = __ballot(cls == 2 && (i & 1) == half);
        int pch = (int)__popcll(mch & ((1ull << i) - 1ull));
        int p23 = (int)__popcll(m23 & ((1ull << i) - 1ull));
        if (half == 0 && cls == 1) g_chain[bt][pch] = (i << 16) | sp;
        if (cls == 2 && (i & 1) == half) m23l_s[p23] = (i << 16) | sp;
        if (i == 0){
            nf23_s = (int)__popcll(m23);
            if (half == 0) g_nchain[bt] = (int)__popcll(mch);
        }
    }
    // stage co rows for MY m1 rows
    for (int idx = tid; idx < nMy * Gq; idx += 512){
        int il = idx >> 5, g = idx & 31;
        co1_s[il][g] = g_co[bt][g_mapc[bt][l1_s[2 * il + half]]][g];
    }
    __syncthreads();

    // cooperative gi: thread j < 450 holds Wi column in regs (Wi read once per block, coalesced)
    if (tid < H3q){
        float wcol[Gq];
        #pragma unroll
        for (int g = 0; g < Gq; ++g) wcol[g] = Wi[g * H3q + tid];
        float bij = bi[tid];
        for (int il = 0; il < nMy; ++il){
            float acc = bij;
            #pragma unroll
            for (int g = 0; g < Gq; ++g) acc += co1_s[il][g] * wcol[g];
            gi_s[il][tid] = acc;
        }
    }
    __syncthreads();

    // plain rows (mine): hp = 0, gh = bias only. Thread (il,h) sole reader+writer of gi_s[il][h]
    for (int idx = tid; idx < nMy * Hq; idx += 512){
        int il = idx / Hq, h = idx % Hq;
        int i = 2 * il + half;
        if (cls_s[i] != 0) continue;
        float gr = gi_s[il][h], gz = gi_s[il][Hq + h], gn = gi_s[il][2 * Hq + h];
        float r  = sigm(gr + bh[h]);
        float z  = sigm(gz + bh[Hq + h]);
        float ng = tanhf(gn + r * bh[2 * Hq + h]);
        gi_s[il][h] = (1.f - z) * ng;
    }
    __syncthreads();

    // m23-sourced rows in my half (~0.5 per block): full Wh matvec + GRU
    int nf23 = nf23_s;
    for (int f = 0; f < nf23; ++f){
        int pk = m23l_s[f]; int i = pk >> 16, sp = pk & 0xffff;
        int il = i >> 1;
        for (int h = tid; h < Hq; h += 512) hb_s[h] = g_hm23[btp][sp][h];
        __syncthreads();
        for (int j = tid; j < H3q; j += 512){
            float acc = bh[j];
            for (int k2 = 0; k2 < Hq; ++k2) acc += hb_s[k2] * Wh[k2 * H3q + j];
            ghf_s[j] = acc;
        }
        __syncthreads();
        for (int h = tid; h < Hq; h += 512){
            float gr = gi_s[il][h], gz = gi_s[il][Hq + h], gn = gi_s[il][2 * Hq + h];
            float r  = sigm(gr + ghf_s[h]);
            float z  = sigm(gz + ghf_s[Hq + h]);
            float ng = tanhf(gn + r * ghf_s[2 * Hq + h]);
            gi_s[il][h] = (1.f - z) * ng + z * hb_s[h];
        }
        __syncthreads();
    }

    // write my non-chain hm1 + my om1 partial max (chain rows: k_gru1b / k_gru2f)
    for (int idx = tid; idx < nMy * Hq; idx += 512){
        int il = idx / Hq, h = idx % Hq;
        int i = 2 * il + half;
        if (cls_s[i] != 1) g_hm1[bt][i][h] = gi_s[il][h];
    }
    for (int h = tid; h < Hq; h += 512){
        float mx = -1e30f;
        for (int il = 0; il < nMy; ++il)
            if (cls_s[2 * il + half] != 1) mx = fmaxf(mx, gi_s[il][h]);
        g_om1p2[half][bt][h] = mx;
    }
}

// -------- K_gru1b (parallel): depth-1 chain rows; defers deep-chain rows into g_chain2 --------
__global__ __launch_bounds__(512) void k_gru1b(const float* Wi, const float* bi,
                                               const float* Wh, const float* bh){
    int bt = blockIdx.x, tid = threadIdx.x;
    int t = bt % Tq, btp = bt - 1;
    __shared__ unsigned char defer_s[NM_CAP];
    __shared__ float co_s[Gq];
    __shared__ float hb_s[Hq];
    __shared__ float ghf_s[H3q];
    __shared__ float cmax_s[Hq];
    int nch = (t > 0) ? g_nchain[bt] : 0;
    for (int h = tid; h < Hq; h += 512) cmax_s[h] = -1e30f;
    if (tid < 64){
        int c = tid;
        int defer = 0;
        if (c < nch){
            int sp = g_chain[bt][c] & 0xffff;
            defer = (g_cls[btp][sp] == 1) ? 1 : 0;   // source is chain at t-1 -> defer
            defer_s[c] = (unsigned char)defer;
        }
        unsigned long long md = __ballot((c < nch) && defer);
        int pos = (int)__popcll(md & ((1ull << c) - 1ull));
        if ((c < nch) && defer) g_chain2[bt][pos] = g_chain[bt][c];
        if (c == 0) g_nchain2[bt] = (int)__popcll(md);
    }
    __syncthreads();
    for (int c = 0; c < nch; ++c){
        if (defer_s[c]) continue;                    // block-uniform
        int pk = g_chain[bt][c]; int i = pk >> 16, sp = pk & 0xffff;
        if (tid < Gq) co_s[tid] = g_co[bt][g_mapc[bt][g_list1[bt][i]]][tid];
        for (int h = tid; h < Hq; h += 512) hb_s[h] = g_hm1[btp][sp][h];
        __syncthreads();
        for (int j = tid; j < H3q; j += 512){
            float acc = bh[j];
            for (int k2 = 0; k2 < Hq; ++k2) acc += hb_s[k2] * Wh[k2 * H3q + j];
            ghf_s[j] = acc;
        }
        __syncthreads();
        for (int h = tid; h < Hq; h += 512){
            float gr, gz, gn;
            gi3(co_s, Wi, bi, h, gr, gz, gn);
            float r  = sigm(gr + ghf_s[h]);
            float z  = sigm(gz + ghf_s[Hq + h]);
            float ng = tanhf(gn + r * ghf_s[2 * Hq + h]);
            float v  = (1.f - z) * ng + z * hb_s[h];
            g_hm1[bt][i][h] = v;
            cmax_s[h] = fmaxf(cmax_s[h], v);
        }
        __syncthreads();
    }
    for (int h = tid; h < Hq; h += 512) g_om1c[bt][h] = cmax_s[h];
}

// -------- K_gru2f (8 blocks): serial deep-chain rows (~3 total), then outs + attention + classifier
__global__ __launch_bounds__(512) void k_gru2f(const float* Wi, const float* bi,
                                               const float* Wh, const float* bh,
                                               const int* lens, const float* Wd, const float* bd,
                                               const float* ctx, const float* Wc, const float* bc,
                                               float* out){
    int b = blockIdx.x, tid = threadIdx.x;
    __shared__ float co_s[Gq];
    __shared__ float hb_s[Hq];
    __shared__ float ghf_s[H3q];
    __shared__ float outs_s[Tq][Hq];
    __shared__ float wdc_s[Hq];
    __shared__ float score_s[Tq];
    __shared__ float pooled_s[Hq];
    for (int t = 1; t < Tq; ++t){
        int bt = b * Tq + t, btp = bt - 1;
        int nch2 = g_nchain2[bt];
        for (int c = 0; c < nch2; ++c){
            int pk = g_chain2[bt][c]; int i = pk >> 16, sp = pk & 0xffff;
            if (tid < Gq) co_s[tid] = g_co[bt][g_mapc[bt][g_list1[bt][i]]][tid];
            for (int h = tid; h < Hq; h += 512) hb_s[h] = g_hm1[btp][sp][h];
            __syncthreads();
            for (int j = tid; j < H3q; j += 512){
                float acc = bh[j];
                for (int k2 = 0; k2 < Hq; ++k2) acc += hb_s[k2] * Wh[k2 * H3q + j];
                ghf_s[j] = acc;
            }
            __syncthreads();
            for (int h = tid; h < Hq; h += 512){
                float gr, gz, gn;
                gi3(co_s, Wi, bi, h, gr, gz, gn);
                float r  = sigm(gr + ghf_s[h]);
                float z  = sigm(gz + ghf_s[Hq + h]);
                float ng = tanhf(gn + r * ghf_s[2 * Hq + h]);
                g_hm1[bt][i][h] = (1.f - z) * ng + z * hb_s[h];
            }
            __syncthreads();
        }
    }
    // ---- finalize outs + temporal attention + classifier ----
    for (int idx = tid; idx < Tq * Hq; idx += 512){
        int t = idx / Hq, h = idx % Hq;
        int bt = b * Tq + t;
        int n1 = g_n1[bt], n23 = (t > 0) ? g_n23[bt] : 0;
        float o = 0.f;
        if (n1 > 0){
            float mx = fmaxf(fmaxf(g_om1p2[0][bt][h], g_om1p2[1][bt][h]), g_om1c[bt][h]);
            int nd = (t > 0) ? g_nchain2[bt] : 0;
            for (int c = 0; c < nd; ++c){
                int i = g_chain2[bt][c] >> 16;
                mx = fmaxf(mx, g_hm1[bt][i][h]);
            }
            o = mx;
        }
        if (n23 > 0) o += fmaxf(g_om23p2[0][bt][h], g_om23p2[1][bt][h]);
        outs_s[t][h] = o;
    }
    for (int h = tid; h < Hq; h += 512){
        float acc = 0.f;
        for (int d = 0; d < 32; ++d) acc += Wd[h * 32 + d] * ctx[d];
        wdc_s[h] = acc;
    }
    __syncthreads();
    int len = lens[b];
    if (tid < Tq){
        int t = tid;
        float acc = 0.f;
        for (int d = 0; d < 32; ++d) acc += bd[d] * ctx[d];
        for (int h = 0; h < Hq; ++h) acc += outs_s[t][h] * wdc_s[h];
        score_s[t] = (t < len) ? acc : -1e30f;
    }
    __syncthreads();
    if (tid == 0){
        float mx = -1e30f;
        for (int t = 0; t < Tq; ++t) mx = fmaxf(mx, score_s[t]);
        float sum = 0.f;
        for (int t = 0; t < Tq; ++t){ float e = expf(score_s[t] - mx); score_s[t] = e; sum += e; }
        float inv = 1.f / sum;
        for (int t = 0; t < Tq; ++t) score_s[t] *= inv;
    }
    __syncthreads();
    for (int h = tid; h < Hq; h += 512){
        float acc = 0.f;
        for (int t = 0; t < Tq; ++t) acc += score_s[t] * outs_s[t][h];
        pooled_s[h] = acc;
    }
    __syncthreads();
    for (int o = tid; o < OUTq; o += 512){
        float acc = bc[o];
        for (int h = 0; h < Hq; ++h) acc += pooled_s[h] * Wc[h * OUTq + o];
        out[b * OUTq + o] = sigm(acc);
    }
}

extern "C" void kernel_launch(void* const* d_in, const int* in_sizes, int n_in,
                              void* d_out, int out_size, void* d_ws, size_t ws_size,
                              hipStream_t stream){
    const float* code_x    = (const float*)d_in[0];
    const float* divided   = (const float*)d_in[1];
    const float* neighbors = (const float*)d_in[2];
    const int*   lens      = (const int*)  d_in[3];
    const float* adj       = (const float*)d_in[4];
    const float* c_emb     = (const float*)d_in[5];
    const float* n_emb     = (const float*)d_in[6];
    const float* u_emb     = (const float*)d_in[7];
    const float* Wg        = (const float*)d_in[8];
    const float* bg        = (const float*)d_in[9];
    const float* Wi        = (const float*)d_in[10];
    const float* bi        = (const float*)d_in[11];
    const float* Wh        = (const float*)d_in[12];
    const float* bh        = (const float*)d_in[13];
    const float* Wq_       = (const float*)d_in[14];
    const float* bq_       = (const float*)d_in[15];
    const float* Wk_       = (const float*)d_in[16];
    const float* bk_       = (const float*)d_in[17];
    const float* Wv_       = (const float*)d_in[18];
    const float* bv_       = (const float*)d_in[19];
    const float* Wd_       = (const float*)d_in[20];
    const float* bd_       = (const float*)d_in[21];
    const float* ctx       = (const float*)d_in[22];
    const float* Wc_       = (const float*)d_in[23];
    const float* bc_       = (const float*)d_in[24];
    float* out = (float*)d_out;

    hipLaunchKernelGGL(k_pre,   dim3(256),     dim3(256), 0, stream, c_emb, n_emb, Wg);
    hipLaunchKernelGGL(k_co,    dim3(2 * BTq), dim3(512), 0, stream, code_x, neighbors, adj, bg);
    hipLaunchKernelGGL(k_mid,   dim3(2 * BTq), dim3(512), 0, stream, divided, u_emb,
                       Wk_, bk_, Wq_, bq_, Wv_, bv_, bg);
    hipLaunchKernelGGL(k_gru1,  dim3(2 * BTq), dim3(512), 0, stream, Wi, bi, Wh, bh);
    hipLaunchKernelGGL(k_gru1b, dim3(BTq),     dim3(512), 0, stream, Wi, bi, Wh, bh);
    hipLaunchKernelGGL(k_gru2f, dim3(Bq),      dim3(512), 0, stream, Wi, bi, Wh, bh,
                       lens, Wd_, bd_, ctx, Wc_, bc_, out);
}